// Round 2
// baseline (340.904 us; speedup 1.0000x reference)
//
#include <hip/hip_runtime.h>
#include <hip/hip_bf16.h>

// B=4, S=2048, QD=1024, NH=16, KVH=4, DH=64, WIN=256 (additive +1 mask, full softmax)

using short8 = __attribute__((ext_vector_type(8))) short;
using f32x4  = __attribute__((ext_vector_type(4))) float;
using f32x16 = __attribute__((ext_vector_type(16))) float;
using uint2v = __attribute__((ext_vector_type(2))) unsigned int;

#define GLDS(g, l) __builtin_amdgcn_global_load_lds( \
    (const __attribute__((address_space(1))) void*)(g), \
    (__attribute__((address_space(3))) void*)(l), 16, 0, 0)

__device__ __forceinline__ unsigned short f2bf(float f) {
  union { float f; unsigned u; } v; v.f = f;
  unsigned r = v.u + 0x7fffu + ((v.u >> 16) & 1u);
  return (unsigned short)(r >> 16);
}

__device__ __forceinline__ unsigned cvtpk(float lo, float hi) {
  unsigned r;
  asm("v_cvt_pk_bf16_f32 %0, %1, %2" : "=v"(r) : "v"(lo), "v"(hi));
  return r;
}

// ---------------- conversion kernels ----------------
__global__ void cvt_x_kernel(const float* __restrict__ X, unsigned short* __restrict__ Xb) {
  int i = (blockIdx.x * blockDim.x + threadIdx.x) * 4;
  float4 v = *reinterpret_cast<const float4*>(X + i);
  ushort4 o;
  o.x = f2bf(v.x); o.y = f2bf(v.y); o.z = f2bf(v.z); o.w = f2bf(v.w);
  *reinterpret_cast<ushort4*>(Xb + i) = o;
}

__global__ void tr_cvt_kernel(const float* __restrict__ src, unsigned short* __restrict__ dst, int C) {
  int idx = blockIdx.x * blockDim.x + threadIdx.x;
  int c = idx >> 10, r = idx & 1023;
  dst[idx] = f2bf(src[(size_t)r * C + c]);
}

// ---------------- GEMM: A[M][1024] bf16 x Bt[N][1024] bf16 -> epilogue (m97 structure) ----------------
template<int MODE>
__global__ __launch_bounds__(256) void gemm_bt_kernel(
    const unsigned short* __restrict__ A, const unsigned short* __restrict__ Bt,
    unsigned short* __restrict__ Qo, unsigned short* __restrict__ Ko,
    unsigned short* __restrict__ Vto, float* __restrict__ Co)
{
  __shared__ __align__(16) unsigned short As[128 * 32];
  __shared__ __align__(16) unsigned short Bs[128 * 32];
  const int m0 = blockIdx.x * 128;
  const int n0 = blockIdx.y * 128;
  const int t = threadIdx.x;
  const int w = t >> 6, l = t & 63;
  const int wr = w >> 1, wc = w & 1;

  f32x4 acc[4][4] = {};

  const size_t aoff = (size_t)(m0 + w * 16 + (l >> 2)) * 1024 + (size_t)((l & 3) * 8);
  const size_t boff = (size_t)(n0 + w * 16 + (l >> 2)) * 1024 + (size_t)((l & 3) * 8);

  for (int kt = 0; kt < 1024; kt += 32) {
    GLDS(A  + aoff + kt,             &As[w * 512]);
    GLDS(A  + aoff + 64 * 1024 + kt, &As[(w + 4) * 512]);
    GLDS(Bt + boff + kt,             &Bs[w * 512]);
    GLDS(Bt + boff + 64 * 1024 + kt, &Bs[(w + 4) * 512]);
    __syncthreads();

    short8 af[4], bfr[4];
#pragma unroll
    for (int mi = 0; mi < 4; ++mi) {
      int row = wr * 64 + mi * 16 + (l & 15);
      af[mi] = *reinterpret_cast<const short8*>(&As[row * 32 + (l >> 4) * 8]);
    }
#pragma unroll
    for (int ni = 0; ni < 4; ++ni) {
      int row = wc * 64 + ni * 16 + (l & 15);
      bfr[ni] = *reinterpret_cast<const short8*>(&Bs[row * 32 + (l >> 4) * 8]);
    }
#pragma unroll
    for (int mi = 0; mi < 4; ++mi)
#pragma unroll
      for (int ni = 0; ni < 4; ++ni)
        acc[mi][ni] = __builtin_amdgcn_mfma_f32_16x16x32_bf16(af[mi], bfr[ni], acc[mi][ni], 0, 0, 0);
    __syncthreads();
  }

#pragma unroll
  for (int mi = 0; mi < 4; ++mi)
#pragma unroll
    for (int ni = 0; ni < 4; ++ni)
#pragma unroll
      for (int r = 0; r < 4; ++r) {
        int m = m0 + wr * 64 + mi * 16 + (l >> 4) * 4 + r;
        int n = n0 + wc * 64 + ni * 16 + (l & 15);
        float val = acc[mi][ni][r];
        if (MODE == 0) {
          int b = m >> 11, s = m & 2047;
          unsigned short bv = f2bf(val);
          if (n < 1024) {                     // Q -> [B,NH,S,DH]
            int h = n >> 6, d = n & 63;
            Qo[(((size_t)(b * 16 + h) * 2048 + s) << 6) + d] = bv;
          } else if (n < 1280) {              // K -> [B,KVH,S,DH]
            int kvh = (n - 1024) >> 6, d = n & 63;
            Ko[(((size_t)(b * 4 + kvh) * 2048 + s) << 6) + d] = bv;
          } else {                            // V -> transposed [B,KVH,DH,S]
            int kvh = (n - 1280) >> 6, d = n & 63;
            Vto[((size_t)(b * 4 + kvh) * 64 + d) * 2048 + s] = bv;
          }
        } else {
          Co[((size_t)m << 10) + n] = val;    // fp32 out
        }
      }
}

// ---------------- fused flash attention, swapped-QK^T, no-LDS ----------------
// 1024 blocks x 256 thr; wave = one 32-q-row tile. S^T = mfma32x32x16(K, Q^T):
// lane -> q = col = l&31 fixed; keys = (reg&3)+8*(reg>>2)+4*(l>>5). Softmax fully
// in-register (log2 domain), P^T rebuilt as PV B-frag via cvt_pk + permlane32_swap.
__global__ __launch_bounds__(256, 3) void attn_kernel(
    const unsigned short* __restrict__ Q, const unsigned short* __restrict__ Kc,
    const unsigned short* __restrict__ Vt, unsigned short* __restrict__ AO)
{
  const int t = threadIdx.x, w = t >> 6, l = t & 63;
  const int hi = l >> 5, ln = l & 31;

  // bijective XCD swizzle: 1024 blocks, 8 XCDs -> 128 contiguous work units each (8 heads/XCD)
  const int orig = blockIdx.x;
  const int swz = (orig & 7) * 128 + (orig >> 3);
  const int hf = swz >> 4;        // head instance 0..63
  const int qt = swz & 15;        // q-tile group
  const int b = hf >> 4, h = hf & 15, kvh = h >> 2;
  const int q0 = qt * 128 + w * 32;
  const int qrow = q0 + ln;

  const unsigned short* Qp = Q  + ((size_t)(b * 16 + h)  * 2048 + q0) * 64;
  const unsigned short* Kp = Kc + ((size_t)(b * 4 + kvh) * 2048) * 64;
  const unsigned short* Vp = Vt + ((size_t)(b * 4 + kvh) * 64) * 2048;

  // Q B-frags: lane reads Q[q0+ln][kk*16 + hi*8 ..+8]
  short8 qf[4];
#pragma unroll
  for (int kk = 0; kk < 4; ++kk)
    qf[kk] = *reinterpret_cast<const short8*>(Qp + (size_t)ln * 64 + kk * 16 + hi * 8);

  f32x16 oA = {}, oB = {};
  float m = -1e30f, lsum = 0.f;
  const float C1  = 0.125f * 1.44269504f;   // score scale in log2 domain
  const float L2E = 1.44269504f;            // +1 mask in log2 domain

  for (int kv0 = 0; kv0 < 2048; kv0 += 32) {
    // ---- S^T = K Q^T over DH=64 (4 mfma) ----
    f32x16 s = {};
#pragma unroll
    for (int kk = 0; kk < 4; ++kk) {
      short8 kf = *reinterpret_cast<const short8*>(Kp + (size_t)(kv0 + ln) * 64 + kk * 16 + hi * 8);
      s = __builtin_amdgcn_mfma_f32_32x32x16_bf16(kf, qf[kk], s, 0, 0, 0);
    }
    // V^T A-frags (issue early): vf[hh*2+ks] = Vt[hh*32+ln][kv0 + ks*16 + hi*8 ..]
    short8 vf[4];
#pragma unroll
    for (int hh = 0; hh < 2; ++hh)
#pragma unroll
      for (int ks = 0; ks < 2; ++ks)
        vf[hh * 2 + ks] = *reinterpret_cast<const short8*>(
            Vp + (size_t)(hh * 32 + ln) * 2048 + kv0 + ks * 16 + hi * 8);

    // ---- mask + scale into log2 domain ----
    float tv[16];
    const int d = q0 - kv0;
    if (d == 256 || d == -256) {            // mixed tile: per-element mask
      const int qmb = qrow - kv0 - 4 * hi;
#pragma unroll
      for (int r = 0; r < 16; ++r) {
        const int kc = (r & 3) + 8 * (r >> 2);
        int df = qmb - kc; df = df < 0 ? -df : df;
        tv[r] = s[r] * C1 + (df <= 256 ? L2E : 0.f);
      }
    } else {
      const float addc = (d <= 224 && d >= -224) ? L2E : 0.f;  // uniform in/out
#pragma unroll
      for (int r = 0; r < 16; ++r)
        tv[r] = s[r] * C1 + addc;
    }

    // ---- row max: in-register tree + cross-half permlane swap ----
    float t8[8], t4[4], t2[2];
#pragma unroll
    for (int i = 0; i < 8; ++i) t8[i] = fmaxf(tv[i], tv[i + 8]);
#pragma unroll
    for (int i = 0; i < 4; ++i) t4[i] = fmaxf(t8[i], t8[i + 4]);
    t2[0] = fmaxf(t4[0], t4[2]); t2[1] = fmaxf(t4[1], t4[3]);
    float mx = fmaxf(t2[0], t2[1]);
    {
      uint2v sw = __builtin_amdgcn_permlane32_swap(__float_as_uint(mx), __float_as_uint(mx), false, false);
      mx = fmaxf(__uint_as_float(sw[0]), __uint_as_float(sw[1]));
    }
    const float mnew = fmaxf(m, mx);
    if (!__all(mnew - m <= 8.f)) {          // defer-max (T13): rescale only on real growth
      const float f = __builtin_amdgcn_exp2f(m - mnew);
#pragma unroll
      for (int i = 0; i < 16; ++i) { oA[i] *= f; oB[i] *= f; }
      lsum *= f;
      m = mnew;
    }

    // ---- P = exp2(t - m), row sum ----
    float p[16];
#pragma unroll
    for (int i = 0; i < 16; ++i) p[i] = __builtin_amdgcn_exp2f(tv[i] - m);
    float s8[8], s4[4];
#pragma unroll
    for (int i = 0; i < 8; ++i) s8[i] = p[i] + p[i + 8];
#pragma unroll
    for (int i = 0; i < 4; ++i) s4[i] = s8[i] + s8[i + 4];
    float sum = (s4[0] + s4[1]) + (s4[2] + s4[3]);
    {
      uint2v sw = __builtin_amdgcn_permlane32_swap(__float_as_uint(sum), __float_as_uint(sum), false, false);
      sum = __uint_as_float(sw[0]) + __uint_as_float(sw[1]);
    }
    lsum += sum;

    // ---- P^T -> bf16 B-frags (cvt_pk + permlane32_swap), PV ----
#pragma unroll
    for (int ks = 0; ks < 2; ++ks) {
      unsigned a0 = cvtpk(p[ks * 8 + 0], p[ks * 8 + 1]);
      unsigned a1 = cvtpk(p[ks * 8 + 2], p[ks * 8 + 3]);
      unsigned b0 = cvtpk(p[ks * 8 + 4], p[ks * 8 + 5]);
      unsigned b1 = cvtpk(p[ks * 8 + 6], p[ks * 8 + 7]);
      uint2v s0 = __builtin_amdgcn_permlane32_swap(a0, b0, false, false);
      uint2v s1 = __builtin_amdgcn_permlane32_swap(a1, b1, false, false);
      union { unsigned u[4]; short8 v; } pf;
      pf.u[0] = s0[0]; pf.u[1] = s1[0]; pf.u[2] = s0[1]; pf.u[3] = s1[1];
      oA = __builtin_amdgcn_mfma_f32_32x32x16_bf16(vf[ks],     pf.v, oA, 0, 0, 0);
      oB = __builtin_amdgcn_mfma_f32_32x32x16_bf16(vf[2 + ks], pf.v, oB, 0, 0, 0);
    }
  }

  // ---- epilogue: O^T[dh][q] -> AO[b][q][h*64+dh], packed 8B stores ----
  const float inv = 1.f / lsum;
  unsigned short* Op = AO + ((size_t)(b * 2048 + qrow)) * 1024 + h * 64;
#pragma unroll
  for (int qd = 0; qd < 4; ++qd) {
    uint2 wv;
    wv.x = cvtpk(oA[4 * qd + 0] * inv, oA[4 * qd + 1] * inv);
    wv.y = cvtpk(oA[4 * qd + 2] * inv, oA[4 * qd + 3] * inv);
    *reinterpret_cast<uint2*>(Op + qd * 8 + hi * 4) = wv;
  }
#pragma unroll
  for (int qd = 0; qd < 4; ++qd) {
    uint2 wv;
    wv.x = cvtpk(oB[4 * qd + 0] * inv, oB[4 * qd + 1] * inv);
    wv.y = cvtpk(oB[4 * qd + 2] * inv, oB[4 * qd + 3] * inv);
    *reinterpret_cast<uint2*>(Op + 32 + qd * 8 + hi * 4) = wv;
  }
}

// ---------------- launcher ----------------
extern "C" void kernel_launch(void* const* d_in, const int* in_sizes, int n_in,
                              void* d_out, int out_size, void* d_ws, size_t ws_size,
                              hipStream_t stream)
{
  const float* X  = (const float*)d_in[0];
  const float* Wq = (const float*)d_in[1];
  const float* Wk = (const float*)d_in[2];
  const float* Wv = (const float*)d_in[3];
  const float* Wo = (const float*)d_in[4];
  float* out = (float*)d_out;
  char* ws = (char*)d_ws;

  unsigned short* Xb    = (unsigned short*)(ws);                 // [8192][1024]      16 MB
  unsigned short* WqkvT = (unsigned short*)(ws + 16777216);      // [1536][1024]       3 MB
  unsigned short* WoT   = (unsigned short*)(ws + 19922944);      // [1024][1024]       2 MB
  unsigned short* Q     = (unsigned short*)(ws + 22020096);      // [B,NH,S,DH]       16 MB
  unsigned short* Kc    = (unsigned short*)(ws + 38797312);      // [B,KVH,S,DH]       4 MB
  unsigned short* Vt    = (unsigned short*)(ws + 42991616);      // [B,KVH,DH,S]       4 MB
  unsigned short* AO    = (unsigned short*)(ws + 47185920);      // [8192][1024]      16 MB

  cvt_x_kernel<<<8192, 256, 0, stream>>>(X, Xb);
  tr_cvt_kernel<<<4096, 256, 0, stream>>>(Wq, WqkvT, 1024);
  tr_cvt_kernel<<<1024, 256, 0, stream>>>(Wk, WqkvT + 1024 * 1024, 256);
  tr_cvt_kernel<<<1024, 256, 0, stream>>>(Wv, WqkvT + 1280 * 1024, 256);
  tr_cvt_kernel<<<4096, 256, 0, stream>>>(Wo, WoT, 1024);

  gemm_bt_kernel<0><<<dim3(64, 12), 256, 0, stream>>>(Xb, WqkvT, Q, Kc, Vt, nullptr);
  attn_kernel<<<1024, 256, 0, stream>>>(Q, Kc, Vt, AO);
  gemm_bt_kernel<1><<<dim3(64, 8), 256, 0, stream>>>(AO, WoT, nullptr, nullptr, nullptr, out);
}

// Round 3
// 220.423 us; speedup vs baseline: 1.5466x; 1.5466x over previous
//
#include <hip/hip_runtime.h>
#include <hip/hip_bf16.h>

// B=4, S=2048, QD=1024, NH=16, KVH=4, DH=64, WIN=256 (additive +1 mask, full softmax)

using short8 = __attribute__((ext_vector_type(8))) short;
using f32x4  = __attribute__((ext_vector_type(4))) float;
using f32x16 = __attribute__((ext_vector_type(16))) float;
using uint2v = __attribute__((ext_vector_type(2))) unsigned int;

#define GLDS(g, l) __builtin_amdgcn_global_load_lds( \
    (const __attribute__((address_space(1))) void*)(g), \
    (__attribute__((address_space(3))) void*)(l), 16, 0, 0)

__device__ __forceinline__ unsigned short f2bf(float f) {
  union { float f; unsigned u; } v; v.f = f;
  unsigned r = v.u + 0x7fffu + ((v.u >> 16) & 1u);
  return (unsigned short)(r >> 16);
}

__device__ __forceinline__ unsigned cvtpk(float lo, float hi) {
  unsigned r;
  asm("v_cvt_pk_bf16_f32 %0, %1, %2" : "=v"(r) : "v"(lo), "v"(hi));
  return r;
}

// ---------------- conversion kernels ----------------
__global__ void cvt_x_kernel(const float* __restrict__ X, unsigned short* __restrict__ Xb) {
  int i = (blockIdx.x * blockDim.x + threadIdx.x) * 4;
  float4 v = *reinterpret_cast<const float4*>(X + i);
  ushort4 o;
  o.x = f2bf(v.x); o.y = f2bf(v.y); o.z = f2bf(v.z); o.w = f2bf(v.w);
  *reinterpret_cast<ushort4*>(Xb + i) = o;
}

__global__ void tr_cvt_kernel(const float* __restrict__ src, unsigned short* __restrict__ dst, int C) {
  int idx = blockIdx.x * blockDim.x + threadIdx.x;
  int c = idx >> 10, r = idx & 1023;
  dst[idx] = f2bf(src[(size_t)r * C + c]);
}

// ---------------- GEMM: A[M][1024] bf16 x Bt[N][1024] bf16 -> epilogue (m97 structure) ----------------
// MODE 0 epilogue writes Q/K/V in MFMA-FRAGMENT-MAJOR layout (lane-linear 512-elem
// fragments per 32-seq tile) so the attention kernel's loads are fully coalesced.
template<int MODE>
__global__ __launch_bounds__(256) void gemm_bt_kernel(
    const unsigned short* __restrict__ A, const unsigned short* __restrict__ Bt,
    unsigned short* __restrict__ Qo, unsigned short* __restrict__ Ko,
    unsigned short* __restrict__ Vto, float* __restrict__ Co)
{
  __shared__ __align__(16) unsigned short As[128 * 32];
  __shared__ __align__(16) unsigned short Bs[128 * 32];
  const int m0 = blockIdx.x * 128;
  const int n0 = blockIdx.y * 128;
  const int t = threadIdx.x;
  const int w = t >> 6, l = t & 63;
  const int wr = w >> 1, wc = w & 1;

  f32x4 acc[4][4] = {};

  const size_t aoff = (size_t)(m0 + w * 16 + (l >> 2)) * 1024 + (size_t)((l & 3) * 8);
  const size_t boff = (size_t)(n0 + w * 16 + (l >> 2)) * 1024 + (size_t)((l & 3) * 8);

  for (int kt = 0; kt < 1024; kt += 32) {
    GLDS(A  + aoff + kt,             &As[w * 512]);
    GLDS(A  + aoff + 64 * 1024 + kt, &As[(w + 4) * 512]);
    GLDS(Bt + boff + kt,             &Bs[w * 512]);
    GLDS(Bt + boff + 64 * 1024 + kt, &Bs[(w + 4) * 512]);
    __syncthreads();

    short8 af[4], bfr[4];
#pragma unroll
    for (int mi = 0; mi < 4; ++mi) {
      int row = wr * 64 + mi * 16 + (l & 15);
      af[mi] = *reinterpret_cast<const short8*>(&As[row * 32 + (l >> 4) * 8]);
    }
#pragma unroll
    for (int ni = 0; ni < 4; ++ni) {
      int row = wc * 64 + ni * 16 + (l & 15);
      bfr[ni] = *reinterpret_cast<const short8*>(&Bs[row * 32 + (l >> 4) * 8]);
    }
#pragma unroll
    for (int mi = 0; mi < 4; ++mi)
#pragma unroll
      for (int ni = 0; ni < 4; ++ni)
        acc[mi][ni] = __builtin_amdgcn_mfma_f32_16x16x32_bf16(af[mi], bfr[ni], acc[mi][ni], 0, 0, 0);
    __syncthreads();
  }

#pragma unroll
  for (int mi = 0; mi < 4; ++mi)
#pragma unroll
    for (int ni = 0; ni < 4; ++ni)
#pragma unroll
      for (int r = 0; r < 4; ++r) {
        int m = m0 + wr * 64 + mi * 16 + (l >> 4) * 4 + r;
        int n = n0 + wc * 64 + ni * 16 + (l & 15);
        float val = acc[mi][ni][r];
        if (MODE == 0) {
          int b = m >> 11, s = m & 2047;
          unsigned short bv = f2bf(val);
          int T = s >> 5;
          if (n < 1024) {                     // Q fragment-major
            int h = n >> 6, d = n & 63;
            size_t base = ((((size_t)(b * 16 + h)) * 64 + T) * 4 + (d >> 4)) * 512;
            Qo[base + ((d >> 3) & 1) * 256 + (s & 31) * 8 + (d & 7)] = bv;
          } else if (n < 1280) {              // K fragment-major
            int kvh = (n - 1024) >> 6, d = n & 63;
            size_t base = ((((size_t)(b * 4 + kvh)) * 64 + T) * 4 + (d >> 4)) * 512;
            Ko[base + ((d >> 3) & 1) * 256 + (s & 31) * 8 + (d & 7)] = bv;
          } else {                            // V^T fragment-major
            int kvh = (n - 1280) >> 6, d = n & 63;
            size_t base = ((((size_t)(b * 4 + kvh)) * 64 + T) * 4 +
                           ((d >> 5) * 2 + ((s >> 4) & 1))) * 512;
            Vto[base + ((s >> 3) & 1) * 256 + (d & 31) * 8 + (s & 7)] = bv;
          }
        } else {
          Co[((size_t)m << 10) + n] = val;    // fp32 out
        }
      }
}

// ---------------- fused flash attention, swapped-QK^T, no-LDS, fragment-major IO ----------------
// 1024 blocks x 256 thr; wave = one 32-q-row tile. S^T = mfma32x32x16(K, Q^T):
// lane -> q = col = l&31; keys = (reg&3)+8*(reg>>2)+4*(l>>5). Softmax in-register
// (log2 domain); P^T built as PV B-frag via cvt_pk + permlane32_swap. All K/V/Q
// fragment loads are 1KB contiguous per wave (fragment-major workspace layout).
__global__ __launch_bounds__(256, 3) void attn_kernel(
    const unsigned short* __restrict__ Qf, const unsigned short* __restrict__ Kf,
    const unsigned short* __restrict__ Vf, unsigned short* __restrict__ AO)
{
  const int t = threadIdx.x, w = t >> 6, l = t & 63;
  const int hi = l >> 5, ln = l & 31;

  // bijective XCD swizzle: 1024 blocks, 8 XCDs -> 128 contiguous units each (8 heads/XCD)
  const int orig = blockIdx.x;
  const int swz = (orig & 7) * 128 + (orig >> 3);
  const int hf = swz >> 4;        // head instance 0..63
  const int qt = swz & 15;        // q-tile group (4 waves -> 4 consecutive 32-row tiles)
  const int b = hf >> 4, h = hf & 15, kvh = h >> 2;
  const int q0 = qt * 128 + w * 32;
  const int qrow = q0 + ln;

  const unsigned short* Qp = Qf + (((size_t)hf * 64 + qt * 4 + w) * 4) * 512;
  const unsigned short* Kp = Kf + ((size_t)(b * 4 + kvh) * 256) * 512;
  const unsigned short* Vp = Vf + ((size_t)(b * 4 + kvh) * 256) * 512;

  short8 qf[4];
#pragma unroll
  for (int kk = 0; kk < 4; ++kk)
    qf[kk] = *reinterpret_cast<const short8*>(Qp + kk * 512 + l * 8);

  f32x16 oA = {}, oB = {};
  float m = -1e30f, lsum = 0.f;
  const float C1  = 0.125f * 1.44269504f;   // score scale in log2 domain
  const float L2E = 1.44269504f;            // +1 mask in log2 domain

  for (int T = 0; T < 64; ++T) {
    const unsigned short* Kt = Kp + (size_t)T * 2048 + l * 8;
    const unsigned short* Vt = Vp + (size_t)T * 2048 + l * 8;
    // ---- S^T = K Q^T over DH=64 (4 mfma) ----
    f32x16 s = {};
#pragma unroll
    for (int kk = 0; kk < 4; ++kk) {
      short8 kfr = *reinterpret_cast<const short8*>(Kt + kk * 512);
      s = __builtin_amdgcn_mfma_f32_32x32x16_bf16(kfr, qf[kk], s, 0, 0, 0);
    }
    // V^T A-frags (issue early)
    short8 vf[4];
#pragma unroll
    for (int j = 0; j < 4; ++j)
      vf[j] = *reinterpret_cast<const short8*>(Vt + j * 512);

    // ---- mask + scale into log2 domain ----
    float tv[16];
    const int kv0 = T * 32;
    const int d = q0 - kv0;
    if (d == 256 || d == -256) {            // mixed tile: per-element mask
      const int qmb = qrow - kv0 - 4 * hi;
#pragma unroll
      for (int r = 0; r < 16; ++r) {
        const int kc = (r & 3) + 8 * (r >> 2);
        int df = qmb - kc; df = df < 0 ? -df : df;
        tv[r] = s[r] * C1 + (df <= 256 ? L2E : 0.f);
      }
    } else {
      const float addc = (d <= 224 && d >= -224) ? L2E : 0.f;  // uniform in/out
#pragma unroll
      for (int r = 0; r < 16; ++r)
        tv[r] = s[r] * C1 + addc;
    }

    // ---- row max: in-register tree + cross-half permlane swap ----
    float t8[8], t4[4], t2[2];
#pragma unroll
    for (int i = 0; i < 8; ++i) t8[i] = fmaxf(tv[i], tv[i + 8]);
#pragma unroll
    for (int i = 0; i < 4; ++i) t4[i] = fmaxf(t8[i], t8[i + 4]);
    t2[0] = fmaxf(t4[0], t4[2]); t2[1] = fmaxf(t4[1], t4[3]);
    float mx = fmaxf(t2[0], t2[1]);
    {
      uint2v sw = __builtin_amdgcn_permlane32_swap(__float_as_uint(mx), __float_as_uint(mx), false, false);
      mx = fmaxf(__uint_as_float(sw[0]), __uint_as_float(sw[1]));
    }
    const float mnew = fmaxf(m, mx);
    if (!__all(mnew - m <= 8.f)) {          // defer-max (T13)
      const float f = __builtin_amdgcn_exp2f(m - mnew);
#pragma unroll
      for (int i = 0; i < 16; ++i) { oA[i] *= f; oB[i] *= f; }
      lsum *= f;
      m = mnew;
    }

    // ---- P = exp2(t - m), row sum ----
    float p[16];
#pragma unroll
    for (int i = 0; i < 16; ++i) p[i] = __builtin_amdgcn_exp2f(tv[i] - m);
    float s8[8], s4[4];
#pragma unroll
    for (int i = 0; i < 8; ++i) s8[i] = p[i] + p[i + 8];
#pragma unroll
    for (int i = 0; i < 4; ++i) s4[i] = s8[i] + s8[i + 4];
    float sum = (s4[0] + s4[1]) + (s4[2] + s4[3]);
    {
      uint2v sw = __builtin_amdgcn_permlane32_swap(__float_as_uint(sum), __float_as_uint(sum), false, false);
      sum = __uint_as_float(sw[0]) + __uint_as_float(sw[1]);
    }
    lsum += sum;

    // ---- P^T -> bf16 B-frags (cvt_pk + permlane32_swap), PV ----
#pragma unroll
    for (int ks = 0; ks < 2; ++ks) {
      unsigned a0 = cvtpk(p[ks * 8 + 0], p[ks * 8 + 1]);
      unsigned a1 = cvtpk(p[ks * 8 + 2], p[ks * 8 + 3]);
      unsigned b0 = cvtpk(p[ks * 8 + 4], p[ks * 8 + 5]);
      unsigned b1 = cvtpk(p[ks * 8 + 6], p[ks * 8 + 7]);
      uint2v s0 = __builtin_amdgcn_permlane32_swap(a0, b0, false, false);
      uint2v s1 = __builtin_amdgcn_permlane32_swap(a1, b1, false, false);
      union { unsigned u[4]; short8 v; } pf;
      pf.u[0] = s0[0]; pf.u[1] = s1[0]; pf.u[2] = s0[1]; pf.u[3] = s1[1];
      oA = __builtin_amdgcn_mfma_f32_32x32x16_bf16(vf[ks],     pf.v, oA, 0, 0, 0);
      oB = __builtin_amdgcn_mfma_f32_32x32x16_bf16(vf[2 + ks], pf.v, oB, 0, 0, 0);
    }
  }

  // ---- epilogue: O^T[dh][q] -> AO[b][q][h*64+dh], packed 8B stores ----
  const float inv = 1.f / lsum;
  unsigned short* Op = AO + ((size_t)(b * 2048 + qrow)) * 1024 + h * 64;
#pragma unroll
  for (int qd = 0; qd < 4; ++qd) {
    uint2 wv;
    wv.x = cvtpk(oA[4 * qd + 0] * inv, oA[4 * qd + 1] * inv);
    wv.y = cvtpk(oA[4 * qd + 2] * inv, oA[4 * qd + 3] * inv);
    *reinterpret_cast<uint2*>(Op + qd * 8 + hi * 4) = wv;
  }
#pragma unroll
  for (int qd = 0; qd < 4; ++qd) {
    uint2 wv;
    wv.x = cvtpk(oB[4 * qd + 0] * inv, oB[4 * qd + 1] * inv);
    wv.y = cvtpk(oB[4 * qd + 2] * inv, oB[4 * qd + 3] * inv);
    *reinterpret_cast<uint2*>(Op + 32 + qd * 8 + hi * 4) = wv;
  }
}

// ---------------- launcher ----------------
extern "C" void kernel_launch(void* const* d_in, const int* in_sizes, int n_in,
                              void* d_out, int out_size, void* d_ws, size_t ws_size,
                              hipStream_t stream)
{
  const float* X  = (const float*)d_in[0];
  const float* Wq = (const float*)d_in[1];
  const float* Wk = (const float*)d_in[2];
  const float* Wv = (const float*)d_in[3];
  const float* Wo = (const float*)d_in[4];
  float* out = (float*)d_out;
  char* ws = (char*)d_ws;

  unsigned short* Xb    = (unsigned short*)(ws);                 // [8192][1024]      16 MB
  unsigned short* WqkvT = (unsigned short*)(ws + 16777216);      // [1536][1024]       3 MB
  unsigned short* WoT   = (unsigned short*)(ws + 19922944);      // [1024][1024]       2 MB
  unsigned short* Q     = (unsigned short*)(ws + 22020096);      // Q frag-major      16 MB
  unsigned short* Kc    = (unsigned short*)(ws + 38797312);      // K frag-major       4 MB
  unsigned short* Vt    = (unsigned short*)(ws + 42991616);      // V^T frag-major     4 MB
  unsigned short* AO    = (unsigned short*)(ws + 47185920);      // [8192][1024]      16 MB

  cvt_x_kernel<<<8192, 256, 0, stream>>>(X, Xb);
  tr_cvt_kernel<<<4096, 256, 0, stream>>>(Wq, WqkvT, 1024);
  tr_cvt_kernel<<<1024, 256, 0, stream>>>(Wk, WqkvT + 1024 * 1024, 256);
  tr_cvt_kernel<<<1024, 256, 0, stream>>>(Wv, WqkvT + 1280 * 1024, 256);
  tr_cvt_kernel<<<4096, 256, 0, stream>>>(Wo, WoT, 1024);

  gemm_bt_kernel<0><<<dim3(64, 12), 256, 0, stream>>>(Xb, WqkvT, Q, Kc, Vt, nullptr);
  attn_kernel<<<1024, 256, 0, stream>>>(Q, Kc, Vt, AO);
  gemm_bt_kernel<1><<<dim3(64, 8), 256, 0, stream>>>(AO, WoT, nullptr, nullptr, nullptr, out);
}